// Round 7
// baseline (260.982 us; speedup 1.0000x reference)
//
#include <hip/hip_runtime.h>
#include <hip/hip_cooperative_groups.h>
#include <math.h>

namespace cg = cooperative_groups;

#define B_    64
#define L_    512
#define S_    3
#define D_    128
#define OV_   50000
#define VOC_  100000
#define NBLK_ 782   // ceil(OV_/64) for fallback logits kernel

typedef __attribute__((ext_vector_type(8))) short bf16x8;
typedef __attribute__((ext_vector_type(4))) float f32x4;

__device__ __forceinline__ float waveReduceSum(float v) {
#pragma unroll
    for (int off = 32; off >= 1; off >>= 1) v += __shfl_xor(v, off, 64);
    return v;
}
__device__ __forceinline__ float waveReduceMax(float v) {
#pragma unroll
    for (int off = 32; off >= 1; off >>= 1) v = fmaxf(v, __shfl_xor(v, off, 64));
    return v;
}

// fp32 -> bf16 round-to-nearest-even
__device__ __forceinline__ short f2bf(float f) {
    unsigned int u = __float_as_uint(f);
    return (short)((u + 0x7FFFu + ((u >> 16) & 1u)) >> 16);
}

// ---------------------------------------------------------------------------
// K0: P[v] = E[v].W_attn (streamed); zeroes context/hidden/rowsum.
// ---------------------------------------------------------------------------
__global__ __launch_bounds__(256) void prequery_kernel(
    const float* __restrict__ emb, const float* __restrict__ Wa,
    float* __restrict__ P, float* __restrict__ context,
    float* __restrict__ hidden, float* __restrict__ rowsum)
{
    const int tid = threadIdx.x;
    if (blockIdx.x < 64 && tid < D_) {
        context[blockIdx.x * D_ + tid] = 0.f;
        hidden[blockIdx.x * D_ + tid]  = 0.f;
    }
    if (blockIdx.x == 64 && tid < B_) rowsum[tid] = 0.f;

    const int lane = tid & 63;
    const int q = lane >> 4;
    const int j = lane & 15;
    const int waveg = blockIdx.x * 4 + (tid >> 6);
    const int nwaves = gridDim.x * 4;

    const float4 wa0 = ((const float4*)Wa)[2 * j];
    const float4 wa1 = ((const float4*)Wa)[2 * j + 1];

    for (int r0 = waveg * 4; r0 < VOC_; r0 += nwaves * 4) {
        const float4* row = (const float4*)(emb + (long)(r0 + q) * D_ + j * 8);
        float4 e0 = row[0], e1 = row[1];
        float s = e0.x * wa0.x + e0.y * wa0.y + e0.z * wa0.z + e0.w * wa0.w
                + e1.x * wa1.x + e1.y * wa1.y + e1.z * wa1.z + e1.w * wa1.w;
#pragma unroll
        for (int off = 8; off >= 1; off >>= 1) s += __shfl_xor(s, off, 64);
        if (j == 0) P[r0 + q] = s;
    }
}

// ===========================================================================
// Device helper: word softmax for batch b into s_imp (weights*1/3).
// ===========================================================================
__device__ __forceinline__ void word_softmax(
    const int* in_b, const int* __restrict__ mask, const float* __restrict__ P,
    float babias, int b, float* s_imp, float* s_red)
{
    const int tid = threadIdx.x;
    const int wave = tid >> 6, lane = tid & 63;
#pragma unroll
    for (int half = 0; half < 2; ++half) {
        const int l = tid + half * 256;
        float acc = 0.f;
#pragma unroll
        for (int s = 0; s < S_; ++s) {
            int idx = in_b[l * S_ + s];
            if (idx != 0) acc += P[idx];
        }
        float imp = acc * (1.0f / 3.0f) + babias;
        s_imp[l] = mask[b * L_ + l] ? -INFINITY : imp;
    }
    __syncthreads();

    float v0 = s_imp[tid], v1 = s_imp[tid + 256];
    float m = waveReduceMax(fmaxf(v0, v1));
    if (lane == 0) s_red[wave] = m;
    __syncthreads();
    m = fmaxf(fmaxf(s_red[0], s_red[1]), fmaxf(s_red[2], s_red[3]));
    __syncthreads();
    float p0 = expf(v0 - m), p1 = expf(v1 - m);
    float ssum = waveReduceSum(p0 + p1);
    if (lane == 0) s_red[wave] = ssum;
    __syncthreads();
    float inv = (1.0f / 3.0f) / (s_red[0] + s_red[1] + s_red[2] + s_red[3]);
    s_imp[tid]       = p0 * inv;
    s_imp[tid + 256] = p1 * inv;
    __syncthreads();
}

// ---------------------------------------------------------------------------
// K1-coop (B*8 = 512 blocks, 2 blocks/CU): word softmax + context (phase A),
// grid.sync, sense + hidden (phase B) from register-held embeddings.
// ---------------------------------------------------------------------------
__global__ __launch_bounds__(256, 2) void attn_fused(
    const int* __restrict__ inputs, const int* __restrict__ mask,
    const float* __restrict__ P, const float* __restrict__ ba,
    const float* __restrict__ emb, const float* __restrict__ lwp,
    float* __restrict__ context, float* __restrict__ hidden)
{
    cg::grid_group grid = cg::this_grid();

    const int b    = blockIdx.x >> 3;
    const int base = (blockIdx.x & 7) * 64;
    const int tid  = threadIdx.x;
    const int wave = tid >> 6, lane = tid & 63;
    const int h = lane >> 5, j = lane & 31;

    __shared__ float s_imp[L_];
    __shared__ float s_red[4];
    __shared__ float s_part[8][D_];

    const int* in_b = inputs + b * (L_ * S_);
    word_softmax(in_b, mask, P, ba[0], b, s_imp, s_red);

    // ---- phase A: gather 64 words once into regs + context partial ----
    float4 ereg[8][3];
    int    pmask[8];
    float4 c = make_float4(0.f, 0.f, 0.f, 0.f);
#pragma unroll
    for (int it = 0; it < 8; ++it) {
        const int l = base + (wave + it * 4) * 2 + h;
        const float w = s_imp[l];
        int pm = 0;
        float4 mm = make_float4(0.f, 0.f, 0.f, 0.f);
#pragma unroll
        for (int s = 0; s < S_; ++s) {
            int idx = in_b[l * S_ + s];
            float4 e = make_float4(0.f, 0.f, 0.f, 0.f);
            if (idx != 0) {
                e = ((const float4*)(emb + (long)idx * D_))[j];
                pm |= (1 << s);
            }
            ereg[it][s] = e;
            mm.x += e.x; mm.y += e.y; mm.z += e.z; mm.w += e.w;
        }
        pmask[it] = pm;
        c.x += w * mm.x; c.y += w * mm.y; c.z += w * mm.z; c.w += w * mm.w;
    }
    ((float4*)s_part[wave * 2 + h])[j] = c;
    __syncthreads();
    if (tid < D_) {
        float acc = 0.f;
#pragma unroll
        for (int p = 0; p < 8; ++p) acc += s_part[p][tid];
        atomicAdd(&context[b * D_ + tid], acc);
    }

    grid.sync();

    // ---- phase B: sense softmax + hidden from registers ----
    const float lwb = lwp[b];
    const float4 c4 = ((const float4*)(context + b * D_))[j];

    float4 hacc = make_float4(0.f, 0.f, 0.f, 0.f);
#pragma unroll
    for (int it = 0; it < 8; ++it) {
        float sim[S_];
#pragma unroll
        for (int s = 0; s < S_; ++s) {
            float4 e = ereg[it][s];
            sim[s] = e.x * c4.x + e.y * c4.y + e.z * c4.z + e.w * c4.w;
        }
#pragma unroll
        for (int off = 16; off >= 1; off >>= 1) {
            sim[0] += __shfl_xor(sim[0], off, 64);
            sim[1] += __shfl_xor(sim[1], off, 64);
            sim[2] += __shfl_xor(sim[2], off, 64);
        }
        float e0 = expf(sim[0]), e1 = expf(sim[1]), e2 = expf(sim[2]);
        float f = lwb / (e0 + e1 + e2);
        float w0 = (pmask[it] & 1) ? e0 * f : 0.f;
        float w1 = (pmask[it] & 2) ? e1 * f : 0.f;
        float w2 = (pmask[it] & 4) ? e2 * f : 0.f;
        hacc.x += w0 * ereg[it][0].x + w1 * ereg[it][1].x + w2 * ereg[it][2].x;
        hacc.y += w0 * ereg[it][0].y + w1 * ereg[it][1].y + w2 * ereg[it][2].y;
        hacc.z += w0 * ereg[it][0].z + w1 * ereg[it][1].z + w2 * ereg[it][2].z;
        hacc.w += w0 * ereg[it][0].w + w1 * ereg[it][1].w + w2 * ereg[it][2].w;
    }
    __syncthreads();
    ((float4*)s_part[wave * 2 + h])[j] = hacc;
    __syncthreads();
    if (tid < D_) {
        float acc = 0.f;
#pragma unroll
        for (int p = 0; p < 8; ++p) acc += s_part[p][tid];
        atomicAdd(&hidden[b * D_ + tid], acc);
    }
}

// ---------------------------------------------------------------------------
// K1-fallback A: word softmax + context. B*16 blocks (round-5 proven).
// ---------------------------------------------------------------------------
__global__ __launch_bounds__(256) void context_kernel(
    const int* __restrict__ inputs, const int* __restrict__ mask,
    const float* __restrict__ P, const float* __restrict__ ba,
    const float* __restrict__ emb, float* __restrict__ context)
{
    const int b    = blockIdx.x >> 4;
    const int base = (blockIdx.x & 15) * 32;
    const int tid  = threadIdx.x;
    const int wave = tid >> 6, lane = tid & 63;
    const int h = lane >> 5, j = lane & 31;

    __shared__ float s_imp[L_];
    __shared__ float s_red[4];
    __shared__ float s_part[8][D_];

    const int* in_b = inputs + b * (L_ * S_);
    word_softmax(in_b, mask, P, ba[0], b, s_imp, s_red);

    float4 c = make_float4(0.f, 0.f, 0.f, 0.f);
    for (int wp = wave; wp < 16; wp += 4) {
        const int l = base + wp * 2 + h;
        const float w = s_imp[l];
        float4 mm = make_float4(0.f, 0.f, 0.f, 0.f);
#pragma unroll
        for (int s = 0; s < S_; ++s) {
            int idx = in_b[l * S_ + s];
            if (idx != 0) {
                float4 e = ((const float4*)(emb + (long)idx * D_))[j];
                mm.x += e.x; mm.y += e.y; mm.z += e.z; mm.w += e.w;
            }
        }
        c.x += w * mm.x; c.y += w * mm.y; c.z += w * mm.z; c.w += w * mm.w;
    }
    ((float4*)s_part[wave * 2 + h])[j] = c;
    __syncthreads();
    if (tid < D_) {
        float acc = 0.f;
#pragma unroll
        for (int p = 0; p < 8; ++p) acc += s_part[p][tid];
        atomicAdd(&context[b * D_ + tid], acc);
    }
}

// ---------------------------------------------------------------------------
// K1-fallback B: sense + hidden. B*16 blocks (round-5 proven).
// ---------------------------------------------------------------------------
__global__ __launch_bounds__(256) void sense_kernel(
    const int* __restrict__ inputs, const float* __restrict__ lwp,
    const float* __restrict__ context, const float* __restrict__ emb,
    float* __restrict__ hidden)
{
    const int b    = blockIdx.x >> 4;
    const int base = (blockIdx.x & 15) * 32;
    const int tid  = threadIdx.x;
    const int wave = tid >> 6, lane = tid & 63;
    const int h = lane >> 5, j = lane & 31;

    __shared__ float s_part[8][D_];

    const int* in_b = inputs + b * (L_ * S_);
    const float lwb = lwp[b];
    const float4 c4 = ((const float4*)(context + b * D_))[j];

    float4 hacc = make_float4(0.f, 0.f, 0.f, 0.f);
    for (int wp = wave; wp < 16; wp += 4) {
        const int l = base + wp * 2 + h;
        float4 e[S_]; int id[S_]; float sim[S_];
#pragma unroll
        for (int s = 0; s < S_; ++s) {
            id[s] = in_b[l * S_ + s];
            if (id[s] != 0) e[s] = ((const float4*)(emb + (long)id[s] * D_))[j];
            else e[s] = make_float4(0.f, 0.f, 0.f, 0.f);
            sim[s] = e[s].x * c4.x + e[s].y * c4.y + e[s].z * c4.z + e[s].w * c4.w;
        }
#pragma unroll
        for (int off = 16; off >= 1; off >>= 1) {
            sim[0] += __shfl_xor(sim[0], off, 64);
            sim[1] += __shfl_xor(sim[1], off, 64);
            sim[2] += __shfl_xor(sim[2], off, 64);
        }
        float e0 = expf(sim[0]), e1 = expf(sim[1]), e2 = expf(sim[2]);
        float f = lwb / (e0 + e1 + e2);
        float w0 = (id[0] != 0) ? e0 * f : 0.f;
        float w1 = (id[1] != 0) ? e1 * f : 0.f;
        float w2 = (id[2] != 0) ? e2 * f : 0.f;
        hacc.x += w0 * e[0].x + w1 * e[1].x + w2 * e[2].x;
        hacc.y += w0 * e[0].y + w1 * e[1].y + w2 * e[2].y;
        hacc.z += w0 * e[0].z + w1 * e[1].z + w2 * e[2].z;
        hacc.w += w0 * e[0].w + w1 * e[1].w + w2 * e[2].w;
    }
    ((float4*)s_part[wave * 2 + h])[j] = hacc;
    __syncthreads();
    if (tid < D_) {
        float acc = 0.f;
#pragma unroll
        for (int p = 0; p < 8; ++p) acc += s_part[p][tid];
        atomicAdd(&hidden[b * D_ + tid], acc);
    }
}

// ---------------------------------------------------------------------------
// K2-coop (391 blocks, 2 blocks/CU): MFMA logits, 2 v-tiles of 64 per block,
// acc in regs; sumexp partials -> atomic rowsum; grid.sync; write out.
// ---------------------------------------------------------------------------
__global__ __launch_bounds__(256, 2) void logits_fused(
    const float* __restrict__ hidden, const float* __restrict__ Wl,
    const float* __restrict__ bl, float* __restrict__ rowsum,
    float* __restrict__ out)
{
    cg::grid_group grid = cg::this_grid();

    __shared__ short s_hbf[64][136];
    __shared__ float s_ps[64][4];
    __shared__ float s_logz[64];

    const int tid  = threadIdx.x;
    const int wave = tid >> 6, lane = tid & 63;
    const int m15  = lane & 15, quad = lane >> 4;

    for (int i = tid; i < 2048; i += 256) {
        float4 x = ((const float4*)hidden)[i];
        const int r = i >> 5;
        const int c = (i & 31) * 4;
        short* dst = &s_hbf[r][c];
        dst[0] = f2bf(x.x); dst[1] = f2bf(x.y);
        dst[2] = f2bf(x.z); dst[3] = f2bf(x.w);
    }
    __syncthreads();

    int  v[2];   bool valid[2];  float bias[2];
    f32x4 acc[2][4];
#pragma unroll
    for (int tl = 0; tl < 2; ++tl) {
        v[tl] = blockIdx.x * 128 + tl * 64 + wave * 16 + m15;
        valid[tl] = (v[tl] < OV_);
        const int vc = valid[tl] ? v[tl] : (OV_ - 1);
        bias[tl] = bl[vc];
#pragma unroll
        for (int t = 0; t < 4; ++t) acc[tl][t] = (f32x4){0.f, 0.f, 0.f, 0.f};
        const float* wrow = Wl + (long)vc * D_ + quad * 8;
#pragma unroll
        for (int ks = 0; ks < 4; ++ks) {
            float4 x0 = *(const float4*)(wrow + ks * 32);
            float4 x1 = *(const float4*)(wrow + ks * 32 + 4);
            bf16x8 bfr;
            bfr[0] = f2bf(x0.x); bfr[1] = f2bf(x0.y); bfr[2] = f2bf(x0.z); bfr[3] = f2bf(x0.w);
            bfr[4] = f2bf(x1.x); bfr[5] = f2bf(x1.y); bfr[6] = f2bf(x1.z); bfr[7] = f2bf(x1.w);
#pragma unroll
            for (int t = 0; t < 4; ++t) {
                bf16x8 afr = *(const bf16x8*)&s_hbf[t * 16 + m15][ks * 32 + quad * 8];
                acc[tl][t] = __builtin_amdgcn_mfma_f32_16x16x32_bf16(afr, bfr,
                                                                     acc[tl][t], 0, 0, 0);
            }
        }
    }

    // ---- per-(block,row) sumexp partial over 128 cols (no shift) ----
#pragma unroll
    for (int t = 0; t < 4; ++t) {
#pragma unroll
        for (int r = 0; r < 4; ++r) {
            float se = (valid[0] ? expf(acc[0][t][r] + bias[0]) : 0.f)
                     + (valid[1] ? expf(acc[1][t][r] + bias[1]) : 0.f);
#pragma unroll
            for (int off = 8; off >= 1; off >>= 1) se += __shfl_xor(se, off, 64);
            if (m15 == 0) s_ps[t * 16 + quad * 4 + r][wave] = se;
        }
    }
    __syncthreads();
    if (tid < 64)
        atomicAdd(&rowsum[tid],
                  s_ps[tid][0] + s_ps[tid][1] + s_ps[tid][2] + s_ps[tid][3]);

    grid.sync();

    if (tid < 64) s_logz[tid] = logf(rowsum[tid]);
    __syncthreads();

#pragma unroll
    for (int tl = 0; tl < 2; ++tl) {
        if (!valid[tl]) continue;
#pragma unroll
        for (int t = 0; t < 4; ++t)
#pragma unroll
            for (int r = 0; r < 4; ++r) {
                const int row = t * 16 + quad * 4 + r;
                out[(long)row * OV_ + v[tl]] = acc[tl][t][r] + bias[tl] - s_logz[row];
            }
    }
}

// ---------------------------------------------------------------------------
// K2-fallbacks (round-5 proven): logits+pS, reducez, finalize.
// ---------------------------------------------------------------------------
__global__ __launch_bounds__(256) void logits_kernel(
    const float* __restrict__ hidden, const float* __restrict__ Wl,
    const float* __restrict__ bl, float* __restrict__ logits,
    float* __restrict__ pS)
{
    __shared__ short s_hbf[64][136];
    const int tid  = threadIdx.x;
    const int wave = tid >> 6, lane = tid & 63;
    const int m15  = lane & 15, quad = lane >> 4;
    const int v    = blockIdx.x * 64 + wave * 16 + m15;
    const bool valid = (v < OV_);
    const int vc   = valid ? v : (OV_ - 1);

    for (int i = tid; i < 2048; i += 256) {
        float4 x = ((const float4*)hidden)[i];
        const int r = i >> 5;
        const int c = (i & 31) * 4;
        short* dst = &s_hbf[r][c];
        dst[0] = f2bf(x.x); dst[1] = f2bf(x.y);
        dst[2] = f2bf(x.z); dst[3] = f2bf(x.w);
    }
    __syncthreads();

    f32x4 acc[4];
#pragma unroll
    for (int t = 0; t < 4; ++t) acc[t] = (f32x4){0.f, 0.f, 0.f, 0.f};

    const float* wrow = Wl + (long)vc * D_ + quad * 8;
#pragma unroll
    for (int ks = 0; ks < 4; ++ks) {
        float4 x0 = *(const float4*)(wrow + ks * 32);
        float4 x1 = *(const float4*)(wrow + ks * 32 + 4);
        bf16x8 bfr;
        bfr[0] = f2bf(x0.x); bfr[1] = f2bf(x0.y); bfr[2] = f2bf(x0.z); bfr[3] = f2bf(x0.w);
        bfr[4] = f2bf(x1.x); bfr[5] = f2bf(x1.y); bfr[6] = f2bf(x1.z); bfr[7] = f2bf(x1.w);
#pragma unroll
        for (int t = 0; t < 4; ++t) {
            bf16x8 afr = *(const bf16x8*)&s_hbf[t * 16 + m15][ks * 32 + quad * 8];
            acc[t] = __builtin_amdgcn_mfma_f32_16x16x32_bf16(afr, bfr,
                                                             acc[t], 0, 0, 0);
        }
    }
    const float bias = bl[vc];
    if (valid) {
#pragma unroll
        for (int t = 0; t < 4; ++t)
#pragma unroll
            for (int r = 0; r < 4; ++r) {
                const int row = t * 16 + quad * 4 + r;
                logits[(long)row * OV_ + v] = acc[t][r] + bias;
            }
    }

    __shared__ float s_ps[64][4];
#pragma unroll
    for (int t = 0; t < 4; ++t) {
#pragma unroll
        for (int r = 0; r < 4; ++r) {
            float se = valid ? expf(acc[t][r] + bias) : 0.f;
#pragma unroll
            for (int off = 8; off >= 1; off >>= 1) se += __shfl_xor(se, off, 64);
            if (m15 == 0) s_ps[t * 16 + quad * 4 + r][wave] = se;
        }
    }
    __syncthreads();
    if (tid < 64)
        pS[tid * NBLK_ + blockIdx.x] = s_ps[tid][0] + s_ps[tid][1]
                                     + s_ps[tid][2] + s_ps[tid][3];
}

__global__ __launch_bounds__(256) void reducez_kernel(
    const float* __restrict__ pS, float* __restrict__ logZ)
{
    const int b = blockIdx.x;
    const int tid = threadIdx.x;
    const int wave = tid >> 6, lane = tid & 63;
    const float* rs = pS + b * NBLK_;
    __shared__ float s_red[4];

    float s = 0.f;
    for (int i = tid; i < NBLK_; i += 256) s += rs[i];
    s = waveReduceSum(s);
    if (lane == 0) s_red[wave] = s;
    __syncthreads();
    if (tid == 0)
        logZ[b] = logf(s_red[0] + s_red[1] + s_red[2] + s_red[3]);
}

__global__ __launch_bounds__(256) void finalize_kernel(
    const float* __restrict__ logits, const float* __restrict__ logZ,
    float* __restrict__ out)
{
    const long i4 = (long)blockIdx.x * 256 + threadIdx.x;
    const long e  = i4 * 4;
    const int b = (int)(e / OV_);
    const float z = logZ[b];
    float4 x = ((const float4*)logits)[i4];
    x.x -= z; x.y -= z; x.z -= z; x.w -= z;
    ((float4*)out)[i4] = x;
}

extern "C" void kernel_launch(void* const* d_in, const int* in_sizes, int n_in,
                              void* d_out, int out_size, void* d_ws, size_t ws_size,
                              hipStream_t stream) {
    const int*   inputs = (const int*)d_in[0];
    const float* lw     = (const float*)d_in[1];
    const int*   mask   = (const int*)d_in[2];
    const float* emb    = (const float*)d_in[3];
    const float* Wa     = (const float*)d_in[4];
    const float* ba     = (const float*)d_in[5];
    const float* Wl     = (const float*)d_in[6];
    const float* bl     = (const float*)d_in[7];
    float* out = (float*)d_out;

    float* ws = (float*)d_ws;
    float* hidden  = ws;                           // 8,192
    float* context = ws + 8192;                    // 8,192
    float* rowsum  = ws + 16384;                   // 64
    float* logZ    = ws + 16448;                   // 64
    float* P       = ws + 16512;                   // 100,000
    float* logits  = ws + 116512;                  // 3,200,000 (16B-aligned)
    float* pS      = logits + (long)B_ * OV_;      // 64*782

    prequery_kernel<<<625, 256, 0, stream>>>(emb, Wa, P, context, hidden, rowsum);

    // ---- attention: cooperative fused, with split fallback ----
    {
        void* args[] = { (void*)&inputs, (void*)&mask, (void*)&P, (void*)&ba,
                         (void*)&emb, (void*)&lw, (void*)&context, (void*)&hidden };
        hipError_t e = hipLaunchCooperativeKernel((void*)attn_fused,
                                                  dim3(B_ * 8), dim3(256),
                                                  args, 0, stream);
        if (e != hipSuccess) {
            (void)hipGetLastError();
            context_kernel<<<B_ * 16, 256, 0, stream>>>(inputs, mask, P, ba,
                                                        emb, context);
            sense_kernel<<<B_ * 16, 256, 0, stream>>>(inputs, lw, context, emb,
                                                      hidden);
        }
    }

    // ---- logits + logsoftmax: cooperative fused, with split fallback ----
    {
        void* args[] = { (void*)&hidden, (void*)&Wl, (void*)&bl,
                         (void*)&rowsum, (void*)&out };
        hipError_t e = hipLaunchCooperativeKernel((void*)logits_fused,
                                                  dim3(391), dim3(256),
                                                  args, 0, stream);
        if (e != hipSuccess) {
            (void)hipGetLastError();
            logits_kernel<<<NBLK_, 256, 0, stream>>>(hidden, Wl, bl, logits, pS);
            reducez_kernel<<<B_, 256, 0, stream>>>(pS, logZ);
            finalize_kernel<<<(B_ * OV_) / (4 * 256), 256, 0, stream>>>(logits,
                                                                        logZ, out);
        }
    }
}

// Round 8
// 253.412 us; speedup vs baseline: 1.0299x; 1.0299x over previous
//
#include <hip/hip_runtime.h>
#include <hip/hip_cooperative_groups.h>
#include <math.h>

namespace cg = cooperative_groups;

#define B_    64
#define L_    512
#define S_    3
#define D_    128
#define OV_   50000
#define VOC_  100000
#define NBLK_ 782   // ceil(OV_/64) for fallback logits kernel

typedef __attribute__((ext_vector_type(8))) short bf16x8;
typedef __attribute__((ext_vector_type(4))) float f32x4;

__device__ __forceinline__ float waveReduceSum(float v) {
#pragma unroll
    for (int off = 32; off >= 1; off >>= 1) v += __shfl_xor(v, off, 64);
    return v;
}
__device__ __forceinline__ float waveReduceMax(float v) {
#pragma unroll
    for (int off = 32; off >= 1; off >>= 1) v = fmaxf(v, __shfl_xor(v, off, 64));
    return v;
}

// fp32 -> bf16 round-to-nearest-even (as uint16 in low bits)
__device__ __forceinline__ unsigned int f2bfu(float f) {
    unsigned int u = __float_as_uint(f);
    return (u + 0x7FFFu + ((u >> 16) & 1u)) >> 16;
}
__device__ __forceinline__ short f2bf(float f) { return (short)f2bfu(f); }
__device__ __forceinline__ float bfu2f(unsigned int us) {
    return __uint_as_float(us << 16);
}

// pack float4 -> 4 bf16 in uint2
__device__ __forceinline__ uint2 packbf4(float4 e) {
    uint2 p;
    p.x = f2bfu(e.x) | (f2bfu(e.y) << 16);
    p.y = f2bfu(e.z) | (f2bfu(e.w) << 16);
    return p;
}
__device__ __forceinline__ float4 unpackbf4(uint2 p) {
    return make_float4(bfu2f(p.x & 0xFFFFu), bfu2f(p.x >> 16),
                       bfu2f(p.y & 0xFFFFu), bfu2f(p.y >> 16));
}

// ---------------------------------------------------------------------------
// K0: P[v] = E[v].W_attn (streamed); zeroes context/hidden/rowsum.
// ---------------------------------------------------------------------------
__global__ __launch_bounds__(256) void prequery_kernel(
    const float* __restrict__ emb, const float* __restrict__ Wa,
    float* __restrict__ P, float* __restrict__ context,
    float* __restrict__ hidden, float* __restrict__ rowsum)
{
    const int tid = threadIdx.x;
    if (blockIdx.x < 64 && tid < D_) {
        context[blockIdx.x * D_ + tid] = 0.f;
        hidden[blockIdx.x * D_ + tid]  = 0.f;
    }
    if (blockIdx.x == 64 && tid < B_) rowsum[tid] = 0.f;

    const int lane = tid & 63;
    const int q = lane >> 4;
    const int j = lane & 15;
    const int waveg = blockIdx.x * 4 + (tid >> 6);
    const int nwaves = gridDim.x * 4;

    const float4 wa0 = ((const float4*)Wa)[2 * j];
    const float4 wa1 = ((const float4*)Wa)[2 * j + 1];

    for (int r0 = waveg * 4; r0 < VOC_; r0 += nwaves * 4) {
        const float4* row = (const float4*)(emb + (long)(r0 + q) * D_ + j * 8);
        float4 e0 = row[0], e1 = row[1];
        float s = e0.x * wa0.x + e0.y * wa0.y + e0.z * wa0.z + e0.w * wa0.w
                + e1.x * wa1.x + e1.y * wa1.y + e1.z * wa1.z + e1.w * wa1.w;
#pragma unroll
        for (int off = 8; off >= 1; off >>= 1) s += __shfl_xor(s, off, 64);
        if (j == 0) P[r0 + q] = s;
    }
}

// ===========================================================================
// Device helper: word softmax for batch b into s_imp (weights*1/3).
// ===========================================================================
__device__ __forceinline__ void word_softmax(
    const int* in_b, const int* __restrict__ mask, const float* __restrict__ P,
    float babias, int b, float* s_imp, float* s_red)
{
    const int tid = threadIdx.x;
    const int wave = tid >> 6, lane = tid & 63;
#pragma unroll
    for (int half = 0; half < 2; ++half) {
        const int l = tid + half * 256;
        float acc = 0.f;
#pragma unroll
        for (int s = 0; s < S_; ++s) {
            int idx = in_b[l * S_ + s];
            if (idx != 0) acc += P[idx];
        }
        float imp = acc * (1.0f / 3.0f) + babias;
        s_imp[l] = mask[b * L_ + l] ? -INFINITY : imp;
    }
    __syncthreads();

    float v0 = s_imp[tid], v1 = s_imp[tid + 256];
    float m = waveReduceMax(fmaxf(v0, v1));
    if (lane == 0) s_red[wave] = m;
    __syncthreads();
    m = fmaxf(fmaxf(s_red[0], s_red[1]), fmaxf(s_red[2], s_red[3]));
    __syncthreads();
    float p0 = expf(v0 - m), p1 = expf(v1 - m);
    float ssum = waveReduceSum(p0 + p1);
    if (lane == 0) s_red[wave] = ssum;
    __syncthreads();
    float inv = (1.0f / 3.0f) / (s_red[0] + s_red[1] + s_red[2] + s_red[3]);
    s_imp[tid]       = p0 * inv;
    s_imp[tid + 256] = p1 * inv;
    __syncthreads();
}

// ---------------------------------------------------------------------------
// K1-coop (B*8 = 512 blocks, 2 blocks/CU): word softmax + context (phase A),
// grid.sync, sense + hidden (phase B). Embeddings held across the sync as
// PACKED BF16 (48 VGPRs) — fp32 float4 regs spilled to scratch in R7 (VGPR=84).
// ---------------------------------------------------------------------------
__global__ __launch_bounds__(256, 2) void attn_fused(
    const int* __restrict__ inputs, const int* __restrict__ mask,
    const float* __restrict__ P, const float* __restrict__ ba,
    const float* __restrict__ emb, const float* __restrict__ lwp,
    float* __restrict__ context, float* __restrict__ hidden)
{
    cg::grid_group grid = cg::this_grid();

    const int b    = blockIdx.x >> 3;
    const int base = (blockIdx.x & 7) * 64;
    const int tid  = threadIdx.x;
    const int wave = tid >> 6, lane = tid & 63;
    const int h = lane >> 5, j = lane & 31;

    __shared__ float s_imp[L_];
    __shared__ float s_red[4];
    __shared__ float s_part[8][D_];

    const int* in_b = inputs + b * (L_ * S_);
    word_softmax(in_b, mask, P, ba[0], b, s_imp, s_red);

    // ---- phase A: gather 64 words once; context from fp32; keep bf16 ----
    uint2 ereg[8][3];     // 48 VGPRs
    int   pmask[8];
    float4 c = make_float4(0.f, 0.f, 0.f, 0.f);
#pragma unroll
    for (int it = 0; it < 8; ++it) {
        const int l = base + (wave + it * 4) * 2 + h;
        const float w = s_imp[l];
        int pm = 0;
        float4 mm = make_float4(0.f, 0.f, 0.f, 0.f);
#pragma unroll
        for (int s = 0; s < S_; ++s) {
            int idx = in_b[l * S_ + s];
            float4 e = make_float4(0.f, 0.f, 0.f, 0.f);
            if (idx != 0) {
                e = ((const float4*)(emb + (long)idx * D_))[j];
                pm |= (1 << s);
            }
            ereg[it][s] = packbf4(e);
            mm.x += e.x; mm.y += e.y; mm.z += e.z; mm.w += e.w;
        }
        pmask[it] = pm;
        c.x += w * mm.x; c.y += w * mm.y; c.z += w * mm.z; c.w += w * mm.w;
    }
    ((float4*)s_part[wave * 2 + h])[j] = c;
    __syncthreads();
    if (tid < D_) {
        float acc = 0.f;
#pragma unroll
        for (int p = 0; p < 8; ++p) acc += s_part[p][tid];
        atomicAdd(&context[b * D_ + tid], acc);
    }

    grid.sync();

    // ---- phase B: sense softmax + hidden from bf16-held embeddings ----
    const float lwb = lwp[b];
    const float4 c4 = ((const float4*)(context + b * D_))[j];

    float4 hacc = make_float4(0.f, 0.f, 0.f, 0.f);
#pragma unroll
    for (int it = 0; it < 8; ++it) {
        float4 e[S_]; float sim[S_];
#pragma unroll
        for (int s = 0; s < S_; ++s) {
            e[s] = unpackbf4(ereg[it][s]);
            sim[s] = e[s].x * c4.x + e[s].y * c4.y + e[s].z * c4.z + e[s].w * c4.w;
        }
#pragma unroll
        for (int off = 16; off >= 1; off >>= 1) {
            sim[0] += __shfl_xor(sim[0], off, 64);
            sim[1] += __shfl_xor(sim[1], off, 64);
            sim[2] += __shfl_xor(sim[2], off, 64);
        }
        float e0 = expf(sim[0]), e1 = expf(sim[1]), e2 = expf(sim[2]);
        float f = lwb / (e0 + e1 + e2);
        float w0 = (pmask[it] & 1) ? e0 * f : 0.f;
        float w1 = (pmask[it] & 2) ? e1 * f : 0.f;
        float w2 = (pmask[it] & 4) ? e2 * f : 0.f;
        hacc.x += w0 * e[0].x + w1 * e[1].x + w2 * e[2].x;
        hacc.y += w0 * e[0].y + w1 * e[1].y + w2 * e[2].y;
        hacc.z += w0 * e[0].z + w1 * e[1].z + w2 * e[2].z;
        hacc.w += w0 * e[0].w + w1 * e[1].w + w2 * e[2].w;
    }
    __syncthreads();
    ((float4*)s_part[wave * 2 + h])[j] = hacc;
    __syncthreads();
    if (tid < D_) {
        float acc = 0.f;
#pragma unroll
        for (int p = 0; p < 8; ++p) acc += s_part[p][tid];
        atomicAdd(&hidden[b * D_ + tid], acc);
    }
}

// ---------------------------------------------------------------------------
// K1-fallback A: word softmax + context. B*16 blocks (round-5 proven).
// ---------------------------------------------------------------------------
__global__ __launch_bounds__(256) void context_kernel(
    const int* __restrict__ inputs, const int* __restrict__ mask,
    const float* __restrict__ P, const float* __restrict__ ba,
    const float* __restrict__ emb, float* __restrict__ context)
{
    const int b    = blockIdx.x >> 4;
    const int base = (blockIdx.x & 15) * 32;
    const int tid  = threadIdx.x;
    const int wave = tid >> 6, lane = tid & 63;
    const int h = lane >> 5, j = lane & 31;

    __shared__ float s_imp[L_];
    __shared__ float s_red[4];
    __shared__ float s_part[8][D_];

    const int* in_b = inputs + b * (L_ * S_);
    word_softmax(in_b, mask, P, ba[0], b, s_imp, s_red);

    float4 c = make_float4(0.f, 0.f, 0.f, 0.f);
    for (int wp = wave; wp < 16; wp += 4) {
        const int l = base + wp * 2 + h;
        const float w = s_imp[l];
        float4 mm = make_float4(0.f, 0.f, 0.f, 0.f);
#pragma unroll
        for (int s = 0; s < S_; ++s) {
            int idx = in_b[l * S_ + s];
            if (idx != 0) {
                float4 e = ((const float4*)(emb + (long)idx * D_))[j];
                mm.x += e.x; mm.y += e.y; mm.z += e.z; mm.w += e.w;
            }
        }
        c.x += w * mm.x; c.y += w * mm.y; c.z += w * mm.z; c.w += w * mm.w;
    }
    ((float4*)s_part[wave * 2 + h])[j] = c;
    __syncthreads();
    if (tid < D_) {
        float acc = 0.f;
#pragma unroll
        for (int p = 0; p < 8; ++p) acc += s_part[p][tid];
        atomicAdd(&context[b * D_ + tid], acc);
    }
}

// ---------------------------------------------------------------------------
// K1-fallback B: sense + hidden. B*16 blocks (round-5 proven).
// ---------------------------------------------------------------------------
__global__ __launch_bounds__(256) void sense_kernel(
    const int* __restrict__ inputs, const float* __restrict__ lwp,
    const float* __restrict__ context, const float* __restrict__ emb,
    float* __restrict__ hidden)
{
    const int b    = blockIdx.x >> 4;
    const int base = (blockIdx.x & 15) * 32;
    const int tid  = threadIdx.x;
    const int wave = tid >> 6, lane = tid & 63;
    const int h = lane >> 5, j = lane & 31;

    __shared__ float s_part[8][D_];

    const int* in_b = inputs + b * (L_ * S_);
    const float lwb = lwp[b];
    const float4 c4 = ((const float4*)(context + b * D_))[j];

    float4 hacc = make_float4(0.f, 0.f, 0.f, 0.f);
    for (int wp = wave; wp < 16; wp += 4) {
        const int l = base + wp * 2 + h;
        float4 e[S_]; int id[S_]; float sim[S_];
#pragma unroll
        for (int s = 0; s < S_; ++s) {
            id[s] = in_b[l * S_ + s];
            if (id[s] != 0) e[s] = ((const float4*)(emb + (long)id[s] * D_))[j];
            else e[s] = make_float4(0.f, 0.f, 0.f, 0.f);
            sim[s] = e[s].x * c4.x + e[s].y * c4.y + e[s].z * c4.z + e[s].w * c4.w;
        }
#pragma unroll
        for (int off = 16; off >= 1; off >>= 1) {
            sim[0] += __shfl_xor(sim[0], off, 64);
            sim[1] += __shfl_xor(sim[1], off, 64);
            sim[2] += __shfl_xor(sim[2], off, 64);
        }
        float e0 = expf(sim[0]), e1 = expf(sim[1]), e2 = expf(sim[2]);
        float f = lwb / (e0 + e1 + e2);
        float w0 = (id[0] != 0) ? e0 * f : 0.f;
        float w1 = (id[1] != 0) ? e1 * f : 0.f;
        float w2 = (id[2] != 0) ? e2 * f : 0.f;
        hacc.x += w0 * e[0].x + w1 * e[1].x + w2 * e[2].x;
        hacc.y += w0 * e[0].y + w1 * e[1].y + w2 * e[2].y;
        hacc.z += w0 * e[0].z + w1 * e[1].z + w2 * e[2].z;
        hacc.w += w0 * e[0].w + w1 * e[1].w + w2 * e[2].w;
    }
    ((float4*)s_part[wave * 2 + h])[j] = hacc;
    __syncthreads();
    if (tid < D_) {
        float acc = 0.f;
#pragma unroll
        for (int p = 0; p < 8; ++p) acc += s_part[p][tid];
        atomicAdd(&hidden[b * D_ + tid], acc);
    }
}

// ---------------------------------------------------------------------------
// K2-coop (391 blocks, 2 blocks/CU): MFMA logits, 2 v-tiles of 64 per block,
// acc in regs; sumexp partials -> atomic rowsum; grid.sync; write out.
// ---------------------------------------------------------------------------
__global__ __launch_bounds__(256, 2) void logits_fused(
    const float* __restrict__ hidden, const float* __restrict__ Wl,
    const float* __restrict__ bl, float* __restrict__ rowsum,
    float* __restrict__ out)
{
    cg::grid_group grid = cg::this_grid();

    __shared__ short s_hbf[64][136];
    __shared__ float s_ps[64][4];
    __shared__ float s_logz[64];

    const int tid  = threadIdx.x;
    const int wave = tid >> 6, lane = tid & 63;
    const int m15  = lane & 15, quad = lane >> 4;

    for (int i = tid; i < 2048; i += 256) {
        float4 x = ((const float4*)hidden)[i];
        const int r = i >> 5;
        const int c = (i & 31) * 4;
        short* dst = &s_hbf[r][c];
        dst[0] = f2bf(x.x); dst[1] = f2bf(x.y);
        dst[2] = f2bf(x.z); dst[3] = f2bf(x.w);
    }
    __syncthreads();

    int  v[2];   bool valid[2];  float bias[2];
    f32x4 acc[2][4];
#pragma unroll
    for (int tl = 0; tl < 2; ++tl) {
        v[tl] = blockIdx.x * 128 + tl * 64 + wave * 16 + m15;
        valid[tl] = (v[tl] < OV_);
        const int vc = valid[tl] ? v[tl] : (OV_ - 1);
        bias[tl] = bl[vc];
#pragma unroll
        for (int t = 0; t < 4; ++t) acc[tl][t] = (f32x4){0.f, 0.f, 0.f, 0.f};
        const float* wrow = Wl + (long)vc * D_ + quad * 8;
#pragma unroll
        for (int ks = 0; ks < 4; ++ks) {
            float4 x0 = *(const float4*)(wrow + ks * 32);
            float4 x1 = *(const float4*)(wrow + ks * 32 + 4);
            bf16x8 bfr;
            bfr[0] = f2bf(x0.x); bfr[1] = f2bf(x0.y); bfr[2] = f2bf(x0.z); bfr[3] = f2bf(x0.w);
            bfr[4] = f2bf(x1.x); bfr[5] = f2bf(x1.y); bfr[6] = f2bf(x1.z); bfr[7] = f2bf(x1.w);
#pragma unroll
            for (int t = 0; t < 4; ++t) {
                bf16x8 afr = *(const bf16x8*)&s_hbf[t * 16 + m15][ks * 32 + quad * 8];
                acc[tl][t] = __builtin_amdgcn_mfma_f32_16x16x32_bf16(afr, bfr,
                                                                     acc[tl][t], 0, 0, 0);
            }
        }
    }

    // ---- per-(block,row) sumexp partial over 128 cols (no shift) ----
#pragma unroll
    for (int t = 0; t < 4; ++t) {
#pragma unroll
        for (int r = 0; r < 4; ++r) {
            float se = (valid[0] ? expf(acc[0][t][r] + bias[0]) : 0.f)
                     + (valid[1] ? expf(acc[1][t][r] + bias[1]) : 0.f);
#pragma unroll
            for (int off = 8; off >= 1; off >>= 1) se += __shfl_xor(se, off, 64);
            if (m15 == 0) s_ps[t * 16 + quad * 4 + r][wave] = se;
        }
    }
    __syncthreads();
    if (tid < 64)
        atomicAdd(&rowsum[tid],
                  s_ps[tid][0] + s_ps[tid][1] + s_ps[tid][2] + s_ps[tid][3]);

    grid.sync();

    if (tid < 64) s_logz[tid] = logf(rowsum[tid]);
    __syncthreads();

#pragma unroll
    for (int tl = 0; tl < 2; ++tl) {
        if (!valid[tl]) continue;
#pragma unroll
        for (int t = 0; t < 4; ++t)
#pragma unroll
            for (int r = 0; r < 4; ++r) {
                const int row = t * 16 + quad * 4 + r;
                out[(long)row * OV_ + v[tl]] = acc[tl][t][r] + bias[tl] - s_logz[row];
            }
    }
}

// ---------------------------------------------------------------------------
// K2-fallbacks (round-5 proven): logits+pS, reducez, finalize.
// ---------------------------------------------------------------------------
__global__ __launch_bounds__(256) void logits_kernel(
    const float* __restrict__ hidden, const float* __restrict__ Wl,
    const float* __restrict__ bl, float* __restrict__ logits,
    float* __restrict__ pS)
{
    __shared__ short s_hbf[64][136];
    const int tid  = threadIdx.x;
    const int wave = tid >> 6, lane = tid & 63;
    const int m15  = lane & 15, quad = lane >> 4;
    const int v    = blockIdx.x * 64 + wave * 16 + m15;
    const bool valid = (v < OV_);
    const int vc   = valid ? v : (OV_ - 1);

    for (int i = tid; i < 2048; i += 256) {
        float4 x = ((const float4*)hidden)[i];
        const int r = i >> 5;
        const int c = (i & 31) * 4;
        short* dst = &s_hbf[r][c];
        dst[0] = f2bf(x.x); dst[1] = f2bf(x.y);
        dst[2] = f2bf(x.z); dst[3] = f2bf(x.w);
    }
    __syncthreads();

    f32x4 acc[4];
#pragma unroll
    for (int t = 0; t < 4; ++t) acc[t] = (f32x4){0.f, 0.f, 0.f, 0.f};

    const float* wrow = Wl + (long)vc * D_ + quad * 8;
#pragma unroll
    for (int ks = 0; ks < 4; ++ks) {
        float4 x0 = *(const float4*)(wrow + ks * 32);
        float4 x1 = *(const float4*)(wrow + ks * 32 + 4);
        bf16x8 bfr;
        bfr[0] = f2bf(x0.x); bfr[1] = f2bf(x0.y); bfr[2] = f2bf(x0.z); bfr[3] = f2bf(x0.w);
        bfr[4] = f2bf(x1.x); bfr[5] = f2bf(x1.y); bfr[6] = f2bf(x1.z); bfr[7] = f2bf(x1.w);
#pragma unroll
        for (int t = 0; t < 4; ++t) {
            bf16x8 afr = *(const bf16x8*)&s_hbf[t * 16 + m15][ks * 32 + quad * 8];
            acc[t] = __builtin_amdgcn_mfma_f32_16x16x32_bf16(afr, bfr,
                                                             acc[t], 0, 0, 0);
        }
    }
    const float bias = bl[vc];
    if (valid) {
#pragma unroll
        for (int t = 0; t < 4; ++t)
#pragma unroll
            for (int r = 0; r < 4; ++r) {
                const int row = t * 16 + quad * 4 + r;
                logits[(long)row * OV_ + v] = acc[t][r] + bias;
            }
    }

    __shared__ float s_ps[64][4];
#pragma unroll
    for (int t = 0; t < 4; ++t) {
#pragma unroll
        for (int r = 0; r < 4; ++r) {
            float se = valid ? expf(acc[t][r] + bias) : 0.f;
#pragma unroll
            for (int off = 8; off >= 1; off >>= 1) se += __shfl_xor(se, off, 64);
            if (m15 == 0) s_ps[t * 16 + quad * 4 + r][wave] = se;
        }
    }
    __syncthreads();
    if (tid < 64)
        pS[tid * NBLK_ + blockIdx.x] = s_ps[tid][0] + s_ps[tid][1]
                                     + s_ps[tid][2] + s_ps[tid][3];
}

__global__ __launch_bounds__(256) void reducez_kernel(
    const float* __restrict__ pS, float* __restrict__ logZ)
{
    const int b = blockIdx.x;
    const int tid = threadIdx.x;
    const int wave = tid >> 6, lane = tid & 63;
    const float* rs = pS + b * NBLK_;
    __shared__ float s_red[4];

    float s = 0.f;
    for (int i = tid; i < NBLK_; i += 256) s += rs[i];
    s = waveReduceSum(s);
    if (lane == 0) s_red[wave] = s;
    __syncthreads();
    if (tid == 0)
        logZ[b] = logf(s_red[0] + s_red[1] + s_red[2] + s_red[3]);
}

__global__ __launch_bounds__(256) void finalize_kernel(
    const float* __restrict__ logits, const float* __restrict__ logZ,
    float* __restrict__ out)
{
    const long i4 = (long)blockIdx.x * 256 + threadIdx.x;
    const long e  = i4 * 4;
    const int b = (int)(e / OV_);
    const float z = logZ[b];
    float4 x = ((const float4*)logits)[i4];
    x.x -= z; x.y -= z; x.z -= z; x.w -= z;
    ((float4*)out)[i4] = x;
}

extern "C" void kernel_launch(void* const* d_in, const int* in_sizes, int n_in,
                              void* d_out, int out_size, void* d_ws, size_t ws_size,
                              hipStream_t stream) {
    const int*   inputs = (const int*)d_in[0];
    const float* lw     = (const float*)d_in[1];
    const int*   mask   = (const int*)d_in[2];
    const float* emb    = (const float*)d_in[3];
    const float* Wa     = (const float*)d_in[4];
    const float* ba     = (const float*)d_in[5];
    const float* Wl     = (const float*)d_in[6];
    const float* bl     = (const float*)d_in[7];
    float* out = (float*)d_out;

    float* ws = (float*)d_ws;
    float* hidden  = ws;                           // 8,192
    float* context = ws + 8192;                    // 8,192
    float* rowsum  = ws + 16384;                   // 64
    float* logZ    = ws + 16448;                   // 64
    float* P       = ws + 16512;                   // 100,000
    float* logits  = ws + 116512;                  // 3,200,000 (16B-aligned)
    float* pS      = logits + (long)B_ * OV_;      // 64*782

    prequery_kernel<<<625, 256, 0, stream>>>(emb, Wa, P, context, hidden, rowsum);

    // ---- attention: cooperative fused, with split fallback ----
    {
        void* args[] = { (void*)&inputs, (void*)&mask, (void*)&P, (void*)&ba,
                         (void*)&emb, (void*)&lw, (void*)&context, (void*)&hidden };
        hipError_t e = hipLaunchCooperativeKernel((void*)attn_fused,
                                                  dim3(B_ * 8), dim3(256),
                                                  args, 0, stream);
        if (e != hipSuccess) {
            (void)hipGetLastError();
            context_kernel<<<B_ * 16, 256, 0, stream>>>(inputs, mask, P, ba,
                                                        emb, context);
            sense_kernel<<<B_ * 16, 256, 0, stream>>>(inputs, lw, context, emb,
                                                      hidden);
        }
    }

    // ---- logits + logsoftmax: cooperative fused, with split fallback ----
    {
        void* args[] = { (void*)&hidden, (void*)&Wl, (void*)&bl,
                         (void*)&rowsum, (void*)&out };
        hipError_t e = hipLaunchCooperativeKernel((void*)logits_fused,
                                                  dim3(391), dim3(256),
                                                  args, 0, stream);
        if (e != hipSuccess) {
            (void)hipGetLastError();
            logits_kernel<<<NBLK_, 256, 0, stream>>>(hidden, Wl, bl, logits, pS);
            reducez_kernel<<<B_, 256, 0, stream>>>(pS, logZ);
            finalize_kernel<<<(B_ * OV_) / (4 * 256), 256, 0, stream>>>(logits,
                                                                        logZ, out);
        }
    }
}

// Round 9
// 162.063 us; speedup vs baseline: 1.6104x; 1.5637x over previous
//
#include <hip/hip_runtime.h>
#include <math.h>

#define B_    64
#define L_    512
#define S_    3
#define D_    128
#define OV_   50000
#define VOC_  100000
#define NBLK_ 782   // ceil(OV_/64)

typedef __attribute__((ext_vector_type(8))) short bf16x8;
typedef __attribute__((ext_vector_type(4))) float f32x4;

__device__ __forceinline__ float waveReduceSum(float v) {
#pragma unroll
    for (int off = 32; off >= 1; off >>= 1) v += __shfl_xor(v, off, 64);
    return v;
}
__device__ __forceinline__ float waveReduceMax(float v) {
#pragma unroll
    for (int off = 32; off >= 1; off >>= 1) v = fmaxf(v, __shfl_xor(v, off, 64));
    return v;
}

// fp32 -> bf16 round-to-nearest-even
__device__ __forceinline__ short f2bf(float f) {
    unsigned int u = __float_as_uint(f);
    return (short)((u + 0x7FFFu + ((u >> 16) & 1u)) >> 16);
}

// ---------------------------------------------------------------------------
// K0: P[v] = E[v].W_attn (streamed); zeroes context/hidden.
// ---------------------------------------------------------------------------
__global__ __launch_bounds__(256) void prequery_kernel(
    const float* __restrict__ emb, const float* __restrict__ Wa,
    float* __restrict__ P, float* __restrict__ context,
    float* __restrict__ hidden)
{
    const int tid = threadIdx.x;
    if (blockIdx.x < 64 && tid < D_) {
        context[blockIdx.x * D_ + tid] = 0.f;
        hidden[blockIdx.x * D_ + tid]  = 0.f;
    }

    const int lane = tid & 63;
    const int q = lane >> 4;
    const int j = lane & 15;
    const int waveg = blockIdx.x * 4 + (tid >> 6);
    const int nwaves = gridDim.x * 4;

    const float4 wa0 = ((const float4*)Wa)[2 * j];
    const float4 wa1 = ((const float4*)Wa)[2 * j + 1];

    for (int r0 = waveg * 4; r0 < VOC_; r0 += nwaves * 4) {
        const float4* row = (const float4*)(emb + (long)(r0 + q) * D_ + j * 8);
        float4 e0 = row[0], e1 = row[1];
        float s = e0.x * wa0.x + e0.y * wa0.y + e0.z * wa0.z + e0.w * wa0.w
                + e1.x * wa1.x + e1.y * wa1.y + e1.z * wa1.z + e1.w * wa1.w;
#pragma unroll
        for (int off = 8; off >= 1; off >>= 1) s += __shfl_xor(s, off, 64);
        if (j == 0) P[r0 + q] = s;
    }
}

// ===========================================================================
// Device helper: word softmax for batch b into s_imp (weights * 1/3).
// ===========================================================================
__device__ __forceinline__ void word_softmax(
    const int* in_b, const int* __restrict__ mask, const float* __restrict__ P,
    float babias, int b, float* s_imp, float* s_red)
{
    const int tid = threadIdx.x;
    const int wave = tid >> 6, lane = tid & 63;
#pragma unroll
    for (int half = 0; half < 2; ++half) {
        const int l = tid + half * 256;
        float acc = 0.f;
#pragma unroll
        for (int s = 0; s < S_; ++s) {
            int idx = in_b[l * S_ + s];
            if (idx != 0) acc += P[idx];
        }
        float imp = acc * (1.0f / 3.0f) + babias;
        s_imp[l] = mask[b * L_ + l] ? -INFINITY : imp;
    }
    __syncthreads();

    float v0 = s_imp[tid], v1 = s_imp[tid + 256];
    float m = waveReduceMax(fmaxf(v0, v1));
    if (lane == 0) s_red[wave] = m;
    __syncthreads();
    m = fmaxf(fmaxf(s_red[0], s_red[1]), fmaxf(s_red[2], s_red[3]));
    __syncthreads();
    float p0 = expf(v0 - m), p1 = expf(v1 - m);
    float ssum = waveReduceSum(p0 + p1);
    if (lane == 0) s_red[wave] = ssum;
    __syncthreads();
    float inv = (1.0f / 3.0f) / (s_red[0] + s_red[1] + s_red[2] + s_red[3]);
    s_imp[tid]       = p0 * inv;
    s_imp[tid + 256] = p1 * inv;
    __syncthreads();
}

// ---------------------------------------------------------------------------
// K1: word softmax + context accumulation. B*16 blocks, 32 words each.
// ---------------------------------------------------------------------------
__global__ __launch_bounds__(256) void context_kernel(
    const int* __restrict__ inputs, const int* __restrict__ mask,
    const float* __restrict__ P, const float* __restrict__ ba,
    const float* __restrict__ emb, float* __restrict__ context)
{
    const int b    = blockIdx.x >> 4;
    const int base = (blockIdx.x & 15) * 32;
    const int tid  = threadIdx.x;
    const int wave = tid >> 6, lane = tid & 63;
    const int h = lane >> 5, j = lane & 31;

    __shared__ float s_imp[L_];
    __shared__ float s_red[4];
    __shared__ float s_part[8][D_];

    const int* in_b = inputs + b * (L_ * S_);
    word_softmax(in_b, mask, P, ba[0], b, s_imp, s_red);

    float4 c = make_float4(0.f, 0.f, 0.f, 0.f);
    for (int wp = wave; wp < 16; wp += 4) {
        const int l = base + wp * 2 + h;
        const float w = s_imp[l];
        float4 mm = make_float4(0.f, 0.f, 0.f, 0.f);
#pragma unroll
        for (int s = 0; s < S_; ++s) {
            int idx = in_b[l * S_ + s];
            if (idx != 0) {
                float4 e = ((const float4*)(emb + (long)idx * D_))[j];
                mm.x += e.x; mm.y += e.y; mm.z += e.z; mm.w += e.w;
            }
        }
        c.x += w * mm.x; c.y += w * mm.y; c.z += w * mm.z; c.w += w * mm.w;
    }
    ((float4*)s_part[wave * 2 + h])[j] = c;
    __syncthreads();
    if (tid < D_) {
        float acc = 0.f;
#pragma unroll
        for (int p = 0; p < 8; ++p) acc += s_part[p][tid];
        atomicAdd(&context[b * D_ + tid], acc);
    }
}

// ---------------------------------------------------------------------------
// K2: sense softmax + hidden. B*32 = 2048 blocks, 16 words each (max TLP
// for the L3-latency-bound re-gather; no softmax redundancy here).
// ---------------------------------------------------------------------------
__global__ __launch_bounds__(256) void sense_kernel(
    const int* __restrict__ inputs, const float* __restrict__ lwp,
    const float* __restrict__ context, const float* __restrict__ emb,
    float* __restrict__ hidden)
{
    const int b    = blockIdx.x >> 5;
    const int base = (blockIdx.x & 31) * 16;
    const int tid  = threadIdx.x;
    const int wave = tid >> 6, lane = tid & 63;
    const int h = lane >> 5, j = lane & 31;

    __shared__ float s_part[8][D_];

    const int* in_b = inputs + b * (L_ * S_);
    const float lwb = lwp[b];
    const float4 c4 = ((const float4*)(context + b * D_))[j];

    float4 hacc = make_float4(0.f, 0.f, 0.f, 0.f);
    for (int wp = wave; wp < 8; wp += 4) {
        const int l = base + wp * 2 + h;
        float4 e[S_]; int id[S_]; float sim[S_];
#pragma unroll
        for (int s = 0; s < S_; ++s) {
            id[s] = in_b[l * S_ + s];
            if (id[s] != 0) e[s] = ((const float4*)(emb + (long)id[s] * D_))[j];
            else e[s] = make_float4(0.f, 0.f, 0.f, 0.f);
            sim[s] = e[s].x * c4.x + e[s].y * c4.y + e[s].z * c4.z + e[s].w * c4.w;
        }
#pragma unroll
        for (int off = 16; off >= 1; off >>= 1) {
            sim[0] += __shfl_xor(sim[0], off, 64);
            sim[1] += __shfl_xor(sim[1], off, 64);
            sim[2] += __shfl_xor(sim[2], off, 64);
        }
        float e0 = expf(sim[0]), e1 = expf(sim[1]), e2 = expf(sim[2]);
        float f = lwb / (e0 + e1 + e2);
        float w0 = (id[0] != 0) ? e0 * f : 0.f;
        float w1 = (id[1] != 0) ? e1 * f : 0.f;
        float w2 = (id[2] != 0) ? e2 * f : 0.f;
        hacc.x += w0 * e[0].x + w1 * e[1].x + w2 * e[2].x;
        hacc.y += w0 * e[0].y + w1 * e[1].y + w2 * e[2].y;
        hacc.z += w0 * e[0].z + w1 * e[1].z + w2 * e[2].z;
        hacc.w += w0 * e[0].w + w1 * e[1].w + w2 * e[2].w;
    }
    ((float4*)s_part[wave * 2 + h])[j] = hacc;
    __syncthreads();
    if (tid < D_) {
        float acc = 0.f;
#pragma unroll
        for (int p = 0; p < 8; ++p) acc += s_part[p][tid];
        atomicAdd(&hidden[b * D_ + tid], acc);
    }
}

// ---------------------------------------------------------------------------
// K3: logits via MFMA (hidden staged once as bf16 in LDS) + fused no-shift
// sumexp partials pS[row][block]. 782 blocks (round-5 proven).
// ---------------------------------------------------------------------------
__global__ __launch_bounds__(256) void logits_kernel(
    const float* __restrict__ hidden, const float* __restrict__ Wl,
    const float* __restrict__ bl, float* __restrict__ logits,
    float* __restrict__ pS)
{
    __shared__ short s_hbf[64][136];
    const int tid  = threadIdx.x;
    const int wave = tid >> 6, lane = tid & 63;
    const int m15  = lane & 15, quad = lane >> 4;
    const int v    = blockIdx.x * 64 + wave * 16 + m15;
    const bool valid = (v < OV_);
    const int vc   = valid ? v : (OV_ - 1);

    for (int i = tid; i < 2048; i += 256) {
        float4 x = ((const float4*)hidden)[i];
        const int r = i >> 5;
        const int c = (i & 31) * 4;
        short* dst = &s_hbf[r][c];
        dst[0] = f2bf(x.x); dst[1] = f2bf(x.y);
        dst[2] = f2bf(x.z); dst[3] = f2bf(x.w);
    }
    __syncthreads();

    f32x4 acc[4];
#pragma unroll
    for (int t = 0; t < 4; ++t) acc[t] = (f32x4){0.f, 0.f, 0.f, 0.f};

    const float* wrow = Wl + (long)vc * D_ + quad * 8;
#pragma unroll
    for (int ks = 0; ks < 4; ++ks) {
        float4 x0 = *(const float4*)(wrow + ks * 32);
        float4 x1 = *(const float4*)(wrow + ks * 32 + 4);
        bf16x8 bfr;
        bfr[0] = f2bf(x0.x); bfr[1] = f2bf(x0.y); bfr[2] = f2bf(x0.z); bfr[3] = f2bf(x0.w);
        bfr[4] = f2bf(x1.x); bfr[5] = f2bf(x1.y); bfr[6] = f2bf(x1.z); bfr[7] = f2bf(x1.w);
#pragma unroll
        for (int t = 0; t < 4; ++t) {
            bf16x8 afr = *(const bf16x8*)&s_hbf[t * 16 + m15][ks * 32 + quad * 8];
            acc[t] = __builtin_amdgcn_mfma_f32_16x16x32_bf16(afr, bfr,
                                                             acc[t], 0, 0, 0);
        }
    }
    const float bias = bl[vc];
    if (valid) {
#pragma unroll
        for (int t = 0; t < 4; ++t)
#pragma unroll
            for (int r = 0; r < 4; ++r) {
                const int row = t * 16 + quad * 4 + r;
                logits[(long)row * OV_ + v] = acc[t][r] + bias;
            }
    }

    __shared__ float s_ps[64][4];
#pragma unroll
    for (int t = 0; t < 4; ++t) {
#pragma unroll
        for (int r = 0; r < 4; ++r) {
            float se = valid ? expf(acc[t][r] + bias) : 0.f;
#pragma unroll
            for (int off = 8; off >= 1; off >>= 1) se += __shfl_xor(se, off, 64);
            if (m15 == 0) s_ps[t * 16 + quad * 4 + r][wave] = se;
        }
    }
    __syncthreads();
    if (tid < 64)
        pS[tid * NBLK_ + blockIdx.x] = s_ps[tid][0] + s_ps[tid][1]
                                     + s_ps[tid][2] + s_ps[tid][3];
}

// ---------------------------------------------------------------------------
// K4: finalize with inline logZ: each block re-sums its row's 782 pS
// partials (L2-hot, ~3 KB) then writes out = logit - logZ. Grid B*49.
// ---------------------------------------------------------------------------
__global__ __launch_bounds__(256) void finalize_kernel(
    const float* __restrict__ logits, const float* __restrict__ pS,
    float* __restrict__ out)
{
    const int b     = blockIdx.x / 49;
    const int chunk = blockIdx.x % 49;
    const int tid   = threadIdx.x;
    const int wave  = tid >> 6, lane = tid & 63;

    __shared__ float s_red[4];
    __shared__ float s_logz;

    const float* rs = pS + b * NBLK_;
    float s = 0.f;
    for (int i = tid; i < NBLK_; i += 256) s += rs[i];
    s = waveReduceSum(s);
    if (lane == 0) s_red[wave] = s;
    __syncthreads();
    if (tid == 0) s_logz = logf(s_red[0] + s_red[1] + s_red[2] + s_red[3]);
    __syncthreads();
    const float z = s_logz;

    const int i4 = chunk * 256 + tid;   // float4 index within the row (12500)
    if (i4 < OV_ / 4) {
        float4 x = ((const float4*)(logits + (long)b * OV_))[i4];
        x.x -= z; x.y -= z; x.z -= z; x.w -= z;
        ((float4*)(out + (long)b * OV_))[i4] = x;
    }
}

extern "C" void kernel_launch(void* const* d_in, const int* in_sizes, int n_in,
                              void* d_out, int out_size, void* d_ws, size_t ws_size,
                              hipStream_t stream) {
    const int*   inputs = (const int*)d_in[0];
    const float* lw     = (const float*)d_in[1];
    const int*   mask   = (const int*)d_in[2];
    const float* emb    = (const float*)d_in[3];
    const float* Wa     = (const float*)d_in[4];
    const float* ba     = (const float*)d_in[5];
    const float* Wl     = (const float*)d_in[6];
    const float* bl     = (const float*)d_in[7];
    float* out = (float*)d_out;

    float* ws = (float*)d_ws;
    float* hidden  = ws;                           // 8,192
    float* context = ws + 8192;                    // 8,192
    float* P       = ws + 16384;                   // 100,000
    float* logits  = ws + 116384 + 96;             // 3,200,000 (16B-aligned)
    float* pS      = logits + (long)B_ * OV_;      // 64*782

    prequery_kernel<<<625, 256, 0, stream>>>(emb, Wa, P, context, hidden);
    context_kernel<<<B_ * 16, 256, 0, stream>>>(inputs, mask, P, ba, emb, context);
    sense_kernel<<<B_ * 32, 256, 0, stream>>>(inputs, lw, context, emb, hidden);
    logits_kernel<<<NBLK_, 256, 0, stream>>>(hidden, Wl, bl, logits, pS);
    finalize_kernel<<<B_ * 49, 256, 0, stream>>>(logits, pS, out);
}

// Round 10
// 154.480 us; speedup vs baseline: 1.6894x; 1.0491x over previous
//
#include <hip/hip_runtime.h>
#include <math.h>

#define B_    64
#define L_    512
#define S_    3
#define D_    128
#define OV_   50000
#define VOC_  100000
#define NBLK_ 782   // ceil(OV_/64)

typedef __attribute__((ext_vector_type(8))) short bf16x8;
typedef __attribute__((ext_vector_type(4))) float f32x4;

__device__ __forceinline__ float waveReduceSum(float v) {
#pragma unroll
    for (int off = 32; off >= 1; off >>= 1) v += __shfl_xor(v, off, 64);
    return v;
}
__device__ __forceinline__ float waveReduceMax(float v) {
#pragma unroll
    for (int off = 32; off >= 1; off >>= 1) v = fmaxf(v, __shfl_xor(v, off, 64));
    return v;
}

// fp32 -> bf16 round-to-nearest-even
__device__ __forceinline__ short f2bf(float f) {
    unsigned int u = __float_as_uint(f);
    return (short)((u + 0x7FFFu + ((u >> 16) & 1u)) >> 16);
}

// ---------------------------------------------------------------------------
// K0: P[v] = E[v].W_attn (streamed); zeroes context/hidden.
// ---------------------------------------------------------------------------
__global__ __launch_bounds__(256) void prequery_kernel(
    const float* __restrict__ emb, const float* __restrict__ Wa,
    float* __restrict__ P, float* __restrict__ context,
    float* __restrict__ hidden)
{
    const int tid = threadIdx.x;
    if (blockIdx.x < 64 && tid < D_) {
        context[blockIdx.x * D_ + tid] = 0.f;
        hidden[blockIdx.x * D_ + tid]  = 0.f;
    }

    const int lane = tid & 63;
    const int q = lane >> 4;
    const int j = lane & 15;
    const int waveg = blockIdx.x * 4 + (tid >> 6);
    const int nwaves = gridDim.x * 4;

    const float4 wa0 = ((const float4*)Wa)[2 * j];
    const float4 wa1 = ((const float4*)Wa)[2 * j + 1];

    for (int r0 = waveg * 4; r0 < VOC_; r0 += nwaves * 4) {
        const float4* row = (const float4*)(emb + (long)(r0 + q) * D_ + j * 8);
        float4 e0 = row[0], e1 = row[1];
        float s = e0.x * wa0.x + e0.y * wa0.y + e0.z * wa0.z + e0.w * wa0.w
                + e1.x * wa1.x + e1.y * wa1.y + e1.z * wa1.z + e1.w * wa1.w;
#pragma unroll
        for (int off = 8; off >= 1; off >>= 1) s += __shfl_xor(s, off, 64);
        if (j == 0) P[r0 + q] = s;
    }
}

// ===========================================================================
// Device helper: word softmax for batch b into s_imp (weights * 1/3).
// Unconditional P loads (P[0] is valid), masked by select after load.
// ===========================================================================
__device__ __forceinline__ void word_softmax(
    const int* in_b, const int* __restrict__ mask, const float* __restrict__ P,
    float babias, int b, float* s_imp, float* s_red)
{
    const int tid = threadIdx.x;
    const int wave = tid >> 6, lane = tid & 63;

    int   idx[2][S_];
    float pv[2][S_];
#pragma unroll
    for (int half = 0; half < 2; ++half) {
        const int l = tid + half * 256;
#pragma unroll
        for (int s = 0; s < S_; ++s) {
            idx[half][s] = in_b[l * S_ + s];
            pv[half][s]  = P[idx[half][s]];
        }
    }
#pragma unroll
    for (int half = 0; half < 2; ++half) {
        const int l = tid + half * 256;
        float acc = 0.f;
#pragma unroll
        for (int s = 0; s < S_; ++s)
            acc += (idx[half][s] != 0) ? pv[half][s] : 0.f;
        float imp = acc * (1.0f / 3.0f) + babias;
        s_imp[l] = mask[b * L_ + l] ? -INFINITY : imp;
    }
    __syncthreads();

    float v0 = s_imp[tid], v1 = s_imp[tid + 256];
    float m = waveReduceMax(fmaxf(v0, v1));
    if (lane == 0) s_red[wave] = m;
    __syncthreads();
    m = fmaxf(fmaxf(s_red[0], s_red[1]), fmaxf(s_red[2], s_red[3]));
    __syncthreads();
    float p0 = expf(v0 - m), p1 = expf(v1 - m);
    float ssum = waveReduceSum(p0 + p1);
    if (lane == 0) s_red[wave] = ssum;
    __syncthreads();
    float inv = (1.0f / 3.0f) / (s_red[0] + s_red[1] + s_red[2] + s_red[3]);
    s_imp[tid]       = p0 * inv;
    s_imp[tid + 256] = p1 * inv;
    __syncthreads();
}

// ---------------------------------------------------------------------------
// K1: word softmax + context. B*16 blocks, 32 words each. Indices staged in
// LDS; 12 UNCONDITIONAL gathers per thread issued as one batch (latency
// overlap); mask folded into the weight after the loads.
// ---------------------------------------------------------------------------
__global__ __launch_bounds__(256) void context_kernel(
    const int* __restrict__ inputs, const int* __restrict__ mask,
    const float* __restrict__ P, const float* __restrict__ ba,
    const float* __restrict__ emb, float* __restrict__ context)
{
    const int b    = blockIdx.x >> 4;
    const int base = (blockIdx.x & 15) * 32;
    const int tid  = threadIdx.x;
    const int wave = tid >> 6, lane = tid & 63;
    const int h = lane >> 5, j = lane & 31;

    __shared__ float s_imp[L_];
    __shared__ float s_red[4];
    __shared__ float s_part[8][D_];
    __shared__ int   s_idx[32 * S_];

    const int* in_b = inputs + b * (L_ * S_);
    if (tid < 32 * S_) s_idx[tid] = in_b[base * S_ + tid];   // visible after
    word_softmax(in_b, mask, P, ba[0], b, s_imp, s_red);     // first sync inside

    // ---- batched unconditional gather: 4 words x 3 senses per thread ----
    int    idx[4][S_];
    float4 e[4][S_];
#pragma unroll
    for (int it = 0; it < 4; ++it) {
        const int lw = (wave + it * 4) * 2 + h;
#pragma unroll
        for (int s = 0; s < S_; ++s) {
            idx[it][s] = s_idx[lw * S_ + s];
            e[it][s]   = ((const float4*)(emb + (long)idx[it][s] * D_))[j];
        }
    }

    float4 c = make_float4(0.f, 0.f, 0.f, 0.f);
#pragma unroll
    for (int it = 0; it < 4; ++it) {
        const int lw = (wave + it * 4) * 2 + h;
        const float w = s_imp[base + lw];
#pragma unroll
        for (int s = 0; s < S_; ++s) {
            const float ws = (idx[it][s] != 0) ? w : 0.f;
            c.x += ws * e[it][s].x; c.y += ws * e[it][s].y;
            c.z += ws * e[it][s].z; c.w += ws * e[it][s].w;
        }
    }
    ((float4*)s_part[wave * 2 + h])[j] = c;
    __syncthreads();
    if (tid < D_) {
        float acc = 0.f;
#pragma unroll
        for (int p = 0; p < 8; ++p) acc += s_part[p][tid];
        atomicAdd(&context[b * D_ + tid], acc);
    }
}

// ---------------------------------------------------------------------------
// K2: sense softmax + hidden. B*32 blocks, 16 words each. Indices in LDS;
// 6 unconditional gathers per thread; mask applied to the reduced sim
// (mask is uniform within the 32-lane reduce group — exact).
// ---------------------------------------------------------------------------
__global__ __launch_bounds__(256) void sense_kernel(
    const int* __restrict__ inputs, const float* __restrict__ lwp,
    const float* __restrict__ context, const float* __restrict__ emb,
    float* __restrict__ hidden)
{
    const int b    = blockIdx.x >> 5;
    const int base = (blockIdx.x & 31) * 16;
    const int tid  = threadIdx.x;
    const int wave = tid >> 6, lane = tid & 63;
    const int h = lane >> 5, j = lane & 31;

    __shared__ float s_part[8][D_];
    __shared__ int   s_idx[16 * S_];

    const int* in_b = inputs + b * (L_ * S_);
    if (tid < 16 * S_) s_idx[tid] = in_b[base * S_ + tid];
    __syncthreads();

    const float lwb = lwp[b];
    const float4 c4 = ((const float4*)(context + b * D_))[j];

    // ---- batched unconditional gather: 2 words x 3 senses per thread ----
    int    idx[2][S_];
    float4 e[2][S_];
#pragma unroll
    for (int it = 0; it < 2; ++it) {
        const int lw = (wave + it * 4) * 2 + h;
#pragma unroll
        for (int s = 0; s < S_; ++s) {
            idx[it][s] = s_idx[lw * S_ + s];
            e[it][s]   = ((const float4*)(emb + (long)idx[it][s] * D_))[j];
        }
    }

    float4 hacc = make_float4(0.f, 0.f, 0.f, 0.f);
#pragma unroll
    for (int it = 0; it < 2; ++it) {
        float sim[S_];
#pragma unroll
        for (int s = 0; s < S_; ++s)
            sim[s] = e[it][s].x * c4.x + e[it][s].y * c4.y
                   + e[it][s].z * c4.z + e[it][s].w * c4.w;
#pragma unroll
        for (int off = 16; off >= 1; off >>= 1) {
            sim[0] += __shfl_xor(sim[0], off, 64);
            sim[1] += __shfl_xor(sim[1], off, 64);
            sim[2] += __shfl_xor(sim[2], off, 64);
        }
        // mask the reduced sims (uniform within reduce group) — exact
        sim[0] = (idx[it][0] != 0) ? sim[0] : 0.f;
        sim[1] = (idx[it][1] != 0) ? sim[1] : 0.f;
        sim[2] = (idx[it][2] != 0) ? sim[2] : 0.f;
        float e0 = expf(sim[0]), e1 = expf(sim[1]), e2 = expf(sim[2]);
        float f = lwb / (e0 + e1 + e2);
        float w0 = (idx[it][0] != 0) ? e0 * f : 0.f;
        float w1 = (idx[it][1] != 0) ? e1 * f : 0.f;
        float w2 = (idx[it][2] != 0) ? e2 * f : 0.f;
        hacc.x += w0 * e[it][0].x + w1 * e[it][1].x + w2 * e[it][2].x;
        hacc.y += w0 * e[it][0].y + w1 * e[it][1].y + w2 * e[it][2].y;
        hacc.z += w0 * e[it][0].z + w1 * e[it][1].z + w2 * e[it][2].z;
        hacc.w += w0 * e[it][0].w + w1 * e[it][1].w + w2 * e[it][2].w;
    }
    ((float4*)s_part[wave * 2 + h])[j] = hacc;
    __syncthreads();
    if (tid < D_) {
        float acc = 0.f;
#pragma unroll
        for (int p = 0; p < 8; ++p) acc += s_part[p][tid];
        atomicAdd(&hidden[b * D_ + tid], acc);
    }
}

// ---------------------------------------------------------------------------
// K3: logits via MFMA (hidden staged once as bf16 in LDS) + fused no-shift
// sumexp partials pS[row][block]. 782 blocks.
// ---------------------------------------------------------------------------
__global__ __launch_bounds__(256) void logits_kernel(
    const float* __restrict__ hidden, const float* __restrict__ Wl,
    const float* __restrict__ bl, float* __restrict__ logits,
    float* __restrict__ pS)
{
    __shared__ short s_hbf[64][136];
    const int tid  = threadIdx.x;
    const int wave = tid >> 6, lane = tid & 63;
    const int m15  = lane & 15, quad = lane >> 4;
    const int v    = blockIdx.x * 64 + wave * 16 + m15;
    const bool valid = (v < OV_);
    const int vc   = valid ? v : (OV_ - 1);

    for (int i = tid; i < 2048; i += 256) {
        float4 x = ((const float4*)hidden)[i];
        const int r = i >> 5;
        const int c = (i & 31) * 4;
        short* dst = &s_hbf[r][c];
        dst[0] = f2bf(x.x); dst[1] = f2bf(x.y);
        dst[2] = f2bf(x.z); dst[3] = f2bf(x.w);
    }
    __syncthreads();

    f32x4 acc[4];
#pragma unroll
    for (int t = 0; t < 4; ++t) acc[t] = (f32x4){0.f, 0.f, 0.f, 0.f};

    const float* wrow = Wl + (long)vc * D_ + quad * 8;
#pragma unroll
    for (int ks = 0; ks < 4; ++ks) {
        float4 x0 = *(const float4*)(wrow + ks * 32);
        float4 x1 = *(const float4*)(wrow + ks * 32 + 4);
        bf16x8 bfr;
        bfr[0] = f2bf(x0.x); bfr[1] = f2bf(x0.y); bfr[2] = f2bf(x0.z); bfr[3] = f2bf(x0.w);
        bfr[4] = f2bf(x1.x); bfr[5] = f2bf(x1.y); bfr[6] = f2bf(x1.z); bfr[7] = f2bf(x1.w);
#pragma unroll
        for (int t = 0; t < 4; ++t) {
            bf16x8 afr = *(const bf16x8*)&s_hbf[t * 16 + m15][ks * 32 + quad * 8];
            acc[t] = __builtin_amdgcn_mfma_f32_16x16x32_bf16(afr, bfr,
                                                             acc[t], 0, 0, 0);
        }
    }
    const float bias = bl[vc];
    if (valid) {
#pragma unroll
        for (int t = 0; t < 4; ++t)
#pragma unroll
            for (int r = 0; r < 4; ++r) {
                const int row = t * 16 + quad * 4 + r;
                logits[(long)row * OV_ + v] = acc[t][r] + bias;
            }
    }

    __shared__ float s_ps[64][4];
#pragma unroll
    for (int t = 0; t < 4; ++t) {
#pragma unroll
        for (int r = 0; r < 4; ++r) {
            float se = valid ? expf(acc[t][r] + bias) : 0.f;
#pragma unroll
            for (int off = 8; off >= 1; off >>= 1) se += __shfl_xor(se, off, 64);
            if (m15 == 0) s_ps[t * 16 + quad * 4 + r][wave] = se;
        }
    }
    __syncthreads();
    if (tid < 64)
        pS[tid * NBLK_ + blockIdx.x] = s_ps[tid][0] + s_ps[tid][1]
                                     + s_ps[tid][2] + s_ps[tid][3];
}

// ---------------------------------------------------------------------------
// K4: finalize with inline logZ (re-sum pS per block, L2-hot). Grid B*49.
// ---------------------------------------------------------------------------
__global__ __launch_bounds__(256) void finalize_kernel(
    const float* __restrict__ logits, const float* __restrict__ pS,
    float* __restrict__ out)
{
    const int b     = blockIdx.x / 49;
    const int chunk = blockIdx.x % 49;
    const int tid   = threadIdx.x;
    const int wave  = tid >> 6, lane = tid & 63;

    __shared__ float s_red[4];
    __shared__ float s_logz;

    const float* rs = pS + b * NBLK_;
    float s = 0.f;
    for (int i = tid; i < NBLK_; i += 256) s += rs[i];
    s = waveReduceSum(s);
    if (lane == 0) s_red[wave] = s;
    __syncthreads();
    if (tid == 0) s_logz = logf(s_red[0] + s_red[1] + s_red[2] + s_red[3]);
    __syncthreads();
    const float z = s_logz;

    const int i4 = chunk * 256 + tid;
    if (i4 < OV_ / 4) {
        float4 x = ((const float4*)(logits + (long)b * OV_))[i4];
        x.x -= z; x.y -= z; x.z -= z; x.w -= z;
        ((float4*)(out + (long)b * OV_))[i4] = x;
    }
}

extern "C" void kernel_launch(void* const* d_in, const int* in_sizes, int n_in,
                              void* d_out, int out_size, void* d_ws, size_t ws_size,
                              hipStream_t stream) {
    const int*   inputs = (const int*)d_in[0];
    const float* lw     = (const float*)d_in[1];
    const int*   mask   = (const int*)d_in[2];
    const float* emb    = (const float*)d_in[3];
    const float* Wa     = (const float*)d_in[4];
    const float* ba     = (const float*)d_in[5];
    const float* Wl     = (const float*)d_in[6];
    const float* bl     = (const float*)d_in[7];
    float* out = (float*)d_out;

    float* ws = (float*)d_ws;
    float* hidden  = ws;                           // 8,192
    float* context = ws + 8192;                    // 8,192
    float* P       = ws + 16384;                   // 100,000
    float* logits  = ws + 116384 + 96;             // 3,200,000 (16B-aligned)
    float* pS      = logits + (long)B_ * OV_;      // 64*782

    prequery_kernel<<<625, 256, 0, stream>>>(emb, Wa, P, context, hidden);
    context_kernel<<<B_ * 16, 256, 0, stream>>>(inputs, mask, P, ba, emb, context);
    sense_kernel<<<B_ * 32, 256, 0, stream>>>(inputs, lw, context, emb, hidden);
    logits_kernel<<<NBLK_, 256, 0, stream>>>(hidden, Wl, bl, logits, pS);
    finalize_kernel<<<B_ * 49, 256, 0, stream>>>(logits, pS, out);
}